// Round 4
// baseline (183.554 us; speedup 1.0000x reference)
//
#include <hip/hip_runtime.h>

// MatrixFactorization: out[n] = dot(concat(Wdow[dow],Wtim[tim],Wmon[mon],Wday[day]), Witem[dest])
//
// Evidence so far:
//  R1 (direct, 32-lane/sample):   91 us, FETCH 297 MB @ 3.24 TB/s
//  R2 (full sort, old compute):   84 us main, FETCH 44 MB  @ 1.0 TB/s (latency-bound) + 194 us sort
//  R3 (direct, 8-lane MLP):       79 us, FETCH 257 MB @ 3.27 TB/s
//  => random 128B-line miss path saturates at ~3.25 TB/s regardless of structure.
//     Lever: cut L2-miss bytes. Fix: cheap 32-bucket dest-binning (no contended
//     global atomics) + XCD-phased main pass so each 1.6 MB W_item segment is
//     fetched once, by one XCD, and stays L2-resident.
//
// ws layout (need = 32768 + 512 + n*8 = 8,421,888 B @ n=1M; proven available in R2):
//   [0,32K)      cnt[q*256+b]  -- pass B overwrites in-place with off[q*256+b]
//   [32K,32K+132) bases[33]     -- exclusive bucket prefix (bases[32] = n)
//   [32K+512,..) payload u64[n]: id:20 | dest:17 | dow:3 | tim:5 | mon:4 | day:5

constexpr int NDIM = 32;
constexpr int SZ_DOW = 7 * NDIM, SZ_TIM = 24 * NDIM, SZ_MON = 12 * NDIM, SZ_DAY = 31 * NDIM;
constexpr int B_DOW = 0;
constexpr int B_TIM = B_DOW + SZ_DOW;   // 224
constexpr int B_MON = B_TIM + SZ_TIM;   // 992
constexpr int B_DAY = B_MON + SZ_MON;   // 1376
constexpr int TAB_TOT = B_DAY + SZ_DAY; // 2368 floats

constexpr int NB   = 32;     // dest-range buckets
constexpr int DDIV = 3125;   // 100000 / 32
constexpr int NBLK = 256;    // blocks in passes A/C

// ---------- Pass A: per-block bucket counts (LDS hist, coalesced write) ----------
__global__ __launch_bounds__(256)
void count_kernel(const int* __restrict__ dest, int* __restrict__ cnt, int n, int spb) {
    __shared__ int h[NB];
    const int t = threadIdx.x, b = blockIdx.x;
    if (t < NB) h[t] = 0;
    __syncthreads();
    const long s0 = (long)b * spb;
    for (int i = t; i < spb; i += 256) {
        const long idx = s0 + i;
        if (idx < n) {
            int q = dest[idx] / DDIV; if (q > NB - 1) q = NB - 1;
            atomicAdd(&h[q], 1);
        }
    }
    __syncthreads();
    if (t < NB) cnt[t * NBLK + b] = h[t];
}

// ---------- Pass B: single-block scan; writes off[] in-place over cnt[], bases[] ----------
__global__ __launch_bounds__(256)
void scan_kernel(int* __restrict__ cntoff, int* __restrict__ bases) {
    __shared__ int c[NB * NBLK];     // 32 KB
    __shared__ int tot[NB + 1];
    const int t = threadIdx.x;
    for (int i = t; i < NB * NBLK; i += 256) c[i] = cntoff[i];
    __syncthreads();
    if (t < NB) { int s = 0; for (int b = 0; b < NBLK; b++) s += c[t * NBLK + b]; tot[t] = s; }
    __syncthreads();
    if (t == 0) {
        int run = 0;
        for (int q = 0; q < NB; q++) { int x = tot[q]; tot[q] = run; run += x; }
        tot[NB] = run;
    }
    __syncthreads();
    if (t <= NB) bases[t] = tot[t];
    if (t < NB) {
        int run = tot[t];
        for (int b = 0; b < NBLK; b++) { cntoff[t * NBLK + b] = run; run += c[t * NBLK + b]; }
    }
}

// ---------- Pass C: bin payload via LDS cursors (no global atomics) ----------
__global__ __launch_bounds__(256)
void scatter_kernel(const int* __restrict__ dow, const int* __restrict__ tim,
                    const int* __restrict__ mon, const int* __restrict__ day,
                    const int* __restrict__ dest, const int* __restrict__ off,
                    unsigned long long* __restrict__ payload, int n, int spb) {
    __shared__ int cur[NB];
    const int t = threadIdx.x, b = blockIdx.x;
    if (t < NB) cur[t] = off[t * NBLK + b];
    __syncthreads();
    const long s0 = (long)b * spb;
    for (int i = t; i < spb; i += 256) {
        const long idx = s0 + i;
        if (idx < n) {
            const int ds = dest[idx];
            int q = ds / DDIV; if (q > NB - 1) q = NB - 1;
            const int pos = atomicAdd(&cur[q], 1);   // LDS atomic, ~2 lanes/bucket/wave
            unsigned long long p = (unsigned long long)(unsigned)idx
                | ((unsigned long long)(unsigned)ds       << 20)
                | ((unsigned long long)(unsigned)dow[idx] << 37)
                | ((unsigned long long)(unsigned)tim[idx] << 40)
                | ((unsigned long long)(unsigned)mon[idx] << 45)
                | ((unsigned long long)(unsigned)day[idx] << 49);
            payload[pos] = p;
        }
    }
}

// ---------- Pass D: XCD-phased binned dot product (R3 compute structure) ----------
__global__ __launch_bounds__(256, 4)
void mf_binned_kernel(const unsigned long long* __restrict__ payload,
                      const float* __restrict__ Wdow, const float* __restrict__ Wtim,
                      const float* __restrict__ Wmon, const float* __restrict__ Wday,
                      const float* __restrict__ Witem,
                      const int* __restrict__ bases, float* __restrict__ out)
{
    __shared__ float tab[TAB_TOT];
    const int tid = threadIdx.x;
    for (int i = tid; i < SZ_DOW; i += 256) tab[B_DOW + i] = Wdow[i];
    for (int i = tid; i < SZ_TIM; i += 256) tab[B_TIM + i] = Wtim[i];
    for (int i = tid; i < SZ_MON; i += 256) tab[B_MON + i] = Wmon[i];
    for (int i = tid; i < SZ_DAY; i += 256) tab[B_DAY + i] = Wday[i];
    __syncthreads();

    const int sub = tid & 63;
    const int wv  = tid >> 6;       // wave in block 0..3
    const int g   = sub >> 3;       // 8-lane group 0..7
    const int l8  = sub & 7;
    const int col = l8 * 4;         // float offset within 32-dim slice
    const int tb[4] = {B_DOW, B_TIM, B_MON, B_DAY};

    const int x = blockIdx.x & 7;   // intended XCD (blockIdx%8 heuristic)
    const int s = blockIdx.x >> 3;  // slot within XCD group: 0..255

    for (int p = 0; p < 4; p++) {
        const int q  = x + 8 * p;          // this XCD's bucket for phase p
        const int qb = bases[q], qe = bases[q + 1];
        const int len = qe - qb;
        const int chunk = (len + 255) >> 8;
        const int st = qb + s * chunk;
        const int en = min(st + chunk, qe);
        const int L  = en - st;

        for (int i = wv * 16; i < L; i += 64) {
            const int i0 = i + g, i1 = i + 8 + g;
            const bool v0 = i0 < L, v1 = i1 < L;

            const unsigned long long p0 = v0 ? payload[st + i0] : 0ull;
            const unsigned long long p1 = v1 ? payload[st + i1] : 0ull;

            const int id0 = (int)(p0 & 0xFFFFFull), d0 = (int)((p0 >> 20) & 0x1FFFFull);
            const int id1 = (int)(p1 & 0xFFFFFull), d1 = (int)((p1 >> 20) & 0x1FFFFull);

            const float* r0 = Witem + (long)d0 * 128 + col;
            const float* r1 = Witem + (long)d1 * 128 + col;

            float4 it0[4], it1[4], us0[4], us1[4];
#pragma unroll
            for (int j = 0; j < 4; j++) it0[j] = *reinterpret_cast<const float4*>(r0 + j * NDIM);
#pragma unroll
            for (int j = 0; j < 4; j++) it1[j] = *reinterpret_cast<const float4*>(r1 + j * NDIM);

            const int sh[4] = {37, 40, 45, 49};
            const int mk[4] = {7, 31, 15, 31};
#pragma unroll
            for (int j = 0; j < 4; j++) {
                const int idx = (int)((p0 >> sh[j]) & (unsigned long long)mk[j]);
                us0[j] = *reinterpret_cast<const float4*>(&tab[tb[j] + idx * NDIM + col]);
            }
#pragma unroll
            for (int j = 0; j < 4; j++) {
                const int idx = (int)((p1 >> sh[j]) & (unsigned long long)mk[j]);
                us1[j] = *reinterpret_cast<const float4*>(&tab[tb[j] + idx * NDIM + col]);
            }

            float a0 = 0.f, a1 = 0.f;
#pragma unroll
            for (int j = 0; j < 4; j++) {
                a0 += it0[j].x * us0[j].x + it0[j].y * us0[j].y
                    + it0[j].z * us0[j].z + it0[j].w * us0[j].w;
                a1 += it1[j].x * us1[j].x + it1[j].y * us1[j].y
                    + it1[j].z * us1[j].z + it1[j].w * us1[j].w;
            }

            a0 += __shfl_xor(a0, 1);  a1 += __shfl_xor(a1, 1);
            a0 += __shfl_xor(a0, 2);  a1 += __shfl_xor(a1, 2);
            a0 += __shfl_xor(a0, 4);  a1 += __shfl_xor(a1, 4);

            if (l8 == 0) {
                if (v0) out[id0] = a0;
                if (v1) out[id1] = a1;
            }
        }
    }
}

// ---------- Fallback: R1 direct kernel (if ws too small / n too large) ----------
__global__ __launch_bounds__(256, 8)
void mf_dot_kernel(const int* __restrict__ dow, const int* __restrict__ tim,
                   const int* __restrict__ mon, const int* __restrict__ day,
                   const int* __restrict__ dest,
                   const float* __restrict__ Wdow, const float* __restrict__ Wtim,
                   const float* __restrict__ Wmon, const float* __restrict__ Wday,
                   const float* __restrict__ Witem,
                   float* __restrict__ out, int n_samples)
{
    __shared__ float tab[TAB_TOT];
    const int tid = threadIdx.x;
    for (int i = tid; i < SZ_DOW; i += 256) tab[B_DOW + i] = Wdow[i];
    for (int i = tid; i < SZ_TIM; i += 256) tab[B_TIM + i] = Wtim[i];
    for (int i = tid; i < SZ_MON; i += 256) tab[B_MON + i] = Wmon[i];
    for (int i = tid; i < SZ_DAY; i += 256) tab[B_DAY + i] = Wday[i];
    __syncthreads();
    const int lane = tid & 63, sub = lane & 31, wave = tid >> 6, half = lane >> 5;
    const int t = sub >> 3, dofs = (sub & 7) * 4;
    const int* idxp  = (t == 0) ? dow   : (t == 1) ? tim   : (t == 2) ? mon   : day;
    const int  tbase = (t == 0) ? B_DOW : (t == 1) ? B_TIM : (t == 2) ? B_MON : B_DAY;
    long n = (long)blockIdx.x * 8 + wave * 2 + half;
    const long stride = (long)gridDim.x * 8;
    for (; n < n_samples; n += stride) {
        const int idx = idxp[n];
        const int ds  = dest[n];
        const float4 u  = *reinterpret_cast<const float4*>(&tab[tbase + idx * NDIM + dofs]);
        const float4 it = *reinterpret_cast<const float4*>(&Witem[(long)ds * 128 + sub * 4]);
        float r = u.x * it.x + u.y * it.y + u.z * it.z + u.w * it.w;
        r += __shfl_xor(r, 16); r += __shfl_xor(r, 8); r += __shfl_xor(r, 4);
        r += __shfl_xor(r, 2);  r += __shfl_xor(r, 1);
        if (sub == 0) out[n] = r;
    }
}

extern "C" void kernel_launch(void* const* d_in, const int* in_sizes, int n_in,
                              void* d_out, int out_size, void* d_ws, size_t ws_size,
                              hipStream_t stream)
{
    const int*   dow   = (const int*)d_in[0];
    const int*   tim   = (const int*)d_in[1];
    const int*   mon   = (const int*)d_in[2];
    const int*   day   = (const int*)d_in[3];
    const int*   dest  = (const int*)d_in[4];
    const float* Wdow  = (const float*)d_in[5];
    const float* Wtim  = (const float*)d_in[6];
    const float* Wmon  = (const float*)d_in[7];
    const float* Wday  = (const float*)d_in[8];
    const float* Witem = (const float*)d_in[9];
    float* out = (float*)d_out;

    const int n = in_sizes[0];  // 1048576

    const size_t payload_off = 32 * 1024 + 512;
    const size_t need = payload_off + (size_t)n * 8;

    if ((size_t)ws_size < need || n > (1 << 20)) {
        hipLaunchKernelGGL(mf_dot_kernel, dim3(2048), dim3(256), 0, stream,
                           dow, tim, mon, day, dest,
                           Wdow, Wtim, Wmon, Wday, Witem, out, n);
        return;
    }

    int* cntoff = (int*)d_ws;                                   // 32K: cnt, then off in-place
    int* bases  = (int*)((char*)d_ws + 32 * 1024);              // 33 ints
    unsigned long long* payload = (unsigned long long*)((char*)d_ws + payload_off);

    const int spb = (n + NBLK - 1) / NBLK;                      // samples per A/C block

    hipLaunchKernelGGL(count_kernel,   dim3(NBLK), dim3(256), 0, stream, dest, cntoff, n, spb);
    hipLaunchKernelGGL(scan_kernel,    dim3(1),    dim3(256), 0, stream, cntoff, bases);
    hipLaunchKernelGGL(scatter_kernel, dim3(NBLK), dim3(256), 0, stream,
                       dow, tim, mon, day, dest, cntoff, payload, n, spb);
    hipLaunchKernelGGL(mf_binned_kernel, dim3(2048), dim3(256), 0, stream,
                       payload, Wdow, Wtim, Wmon, Wday, Witem, bases, out);
}

// Round 5
// 167.837 us; speedup vs baseline: 1.0936x; 1.0936x over previous
//
#include <hip/hip_runtime.h>

// MatrixFactorization: out[n] = dot(concat(Wdow[dow],Wtim[tim],Wmon[mon],Wday[day]), Witem[dest])
//
// Evidence:
//  R1 direct:          main 91 us, FETCH 297 MB @3.24 TB/s (random 128B miss ceiling)
//  R3 direct+MLP:      main 79 us, FETCH 257 MB @3.27 TB/s (same ceiling)
//  R4 32-bucket bin:   main 57 us, FETCH 95 MB, WRITE 32 MB  + ~35 us pre-pass
//    -> scattered 4B out-writes dirty ~4MB of L2 lines per XCD, thrashing the
//       1.6MB item segment; pre-pass dominated by 2x1M serialized LDS atomics.
// R5: (a) single fused bin pass, block-major coalesced payload, no global atomics;
//     (b) main writes res[] in payload order (coalesced); u16 invl permutation
//         (built in LDS) + tiny unperm pass make ALL output traffic coalesced;
//     (c) XCD-phased main unchanged (block bi -> x=bi&7, slice s=bi>>3; phase p
//         processes bucket q=x+8p so each 1.6MB item segment lives on one XCD).
//
// ws layout: [0,32K) cnt[s*32+q] | [32K,64K) lbase[s*32+q] | [64K,+8M) payload u64
//            | [+2M) invl u16 | [+4M) res f32   (full path needs ~14.1 MB;
//            mid path (>=8.07MB) skips invl/res and writes out[id] directly)

constexpr int NDIM = 32;
constexpr int SZ_DOW = 7 * NDIM, SZ_TIM = 24 * NDIM, SZ_MON = 12 * NDIM, SZ_DAY = 31 * NDIM;
constexpr int B_DOW = 0;
constexpr int B_TIM = B_DOW + SZ_DOW;   // 224
constexpr int B_MON = B_TIM + SZ_TIM;   // 992
constexpr int B_DAY = B_MON + SZ_MON;   // 1376
constexpr int TAB_TOT = B_DAY + SZ_DAY; // 2368 floats

constexpr int NB   = 32;      // dest buckets (bucket = dest / 3125, max 31)
constexpr int DDIV = 3125;
constexpr int NBLK = 256;     // slices / bin blocks
constexpr int SPB  = 4096;    // samples per slice

typedef unsigned long long u64;

// ---------- Pass 1: fused count+scan+scatter, per-slice, no global atomics ----------
__global__ __launch_bounds__(256)
void bin_kernel(const int* __restrict__ dow, const int* __restrict__ tim,
                const int* __restrict__ mon, const int* __restrict__ day,
                const int* __restrict__ dest,
                int* __restrict__ cntG, int* __restrict__ lbaseG,
                u64* __restrict__ payload, unsigned short* __restrict__ invl, int n)
{
    __shared__ u64 stage[SPB];              // 32 KB
    __shared__ unsigned short ist[SPB];     // 8 KB
    __shared__ int hist[NB], lbase[NB], cursor[NB];

    const int t = threadIdx.x, b = blockIdx.x;
    const int g0 = b * SPB;
    const int rem = n - g0;
    const int len = rem < SPB ? rem : SPB;  // may be <=0 for tail blocks

    int dreg[16];
#pragma unroll
    for (int i = 0; i < 16; i++) {
        const int k = i * 256 + t;
        dreg[i] = (k < len) ? dest[g0 + k] : -1;
    }
    if (t < NB) hist[t] = 0;
    __syncthreads();
#pragma unroll
    for (int i = 0; i < 16; i++)
        if (dreg[i] >= 0) atomicAdd(&hist[dreg[i] / DDIV], 1);
    __syncthreads();
    if (t == 0) {
        int run = 0;
        for (int q = 0; q < NB; q++) { lbase[q] = run; run += hist[q]; }
    }
    __syncthreads();
    if (t < NB) { cursor[t] = lbase[t]; cntG[b * NB + t] = hist[t]; lbaseG[b * NB + t] = lbase[t]; }
    __syncthreads();
#pragma unroll
    for (int i = 0; i < 16; i++) {
        const int k = i * 256 + t;
        if (k < len) {
            const int ds = dreg[i];
            const int q  = ds / DDIV;
            const int j  = atomicAdd(&cursor[q], 1);         // LDS atomic only
            const u64 p = (u64)(unsigned)(g0 + k)
                | ((u64)(unsigned)ds          << 20)
                | ((u64)(unsigned)dow[g0 + k] << 37)
                | ((u64)(unsigned)tim[g0 + k] << 40)
                | ((u64)(unsigned)mon[g0 + k] << 45)
                | ((u64)(unsigned)day[g0 + k] << 49);
            stage[j] = p;
            ist[k] = (unsigned short)j;
        }
    }
    __syncthreads();
#pragma unroll
    for (int i = 0; i < 16; i++) {
        const int k = i * 256 + t;
        if (k < len) {
            payload[g0 + k] = stage[k];                      // coalesced u64 stream
            if (invl) invl[g0 + k] = ist[k];                 // coalesced u16 stream
        }
    }
}

// ---------- Pass 2: XCD-phased binned dot product (R4 compute structure) ----------
__global__ __launch_bounds__(256, 4)
void mf_main_kernel(const u64* __restrict__ payload,
                    const float* __restrict__ Wdow, const float* __restrict__ Wtim,
                    const float* __restrict__ Wmon, const float* __restrict__ Wday,
                    const float* __restrict__ Witem,
                    const int* __restrict__ cntG, const int* __restrict__ lbaseG,
                    float* __restrict__ res, float* __restrict__ out)
{
    __shared__ float tab[TAB_TOT];
    const int tid = threadIdx.x;
    for (int i = tid; i < SZ_DOW; i += 256) tab[B_DOW + i] = Wdow[i];
    for (int i = tid; i < SZ_TIM; i += 256) tab[B_TIM + i] = Wtim[i];
    for (int i = tid; i < SZ_MON; i += 256) tab[B_MON + i] = Wmon[i];
    for (int i = tid; i < SZ_DAY; i += 256) tab[B_DAY + i] = Wday[i];
    __syncthreads();

    const int sub = tid & 63;
    const int wv  = tid >> 6;       // wave 0..3
    const int g   = sub >> 3;       // 8-lane group 0..7
    const int l8  = sub & 7;
    const int col = l8 * 4;
    const int tb[4] = {B_DOW, B_TIM, B_MON, B_DAY};
    const int sh[4] = {37, 40, 45, 49};
    const int mk[4] = {7, 31, 15, 31};

    const int x = blockIdx.x & 7;   // intended XCD
    const int s = blockIdx.x >> 3;  // slice 0..255

    for (int p = 0; p < 4; p++) {
        const int q  = x + 8 * p;
        const int L  = cntG[s * NB + q];
        const int st = s * SPB + lbaseG[s * NB + q];

        for (int i = wv * 16; i < L; i += 64) {
            const int i0 = i + g, i1 = i + 8 + g;
            const bool v0 = i0 < L, v1 = i1 < L;

            const u64 p0 = v0 ? payload[st + i0] : 0ull;
            const u64 p1 = v1 ? payload[st + i1] : 0ull;

            const int id0 = (int)(p0 & 0xFFFFFull), d0 = (int)((p0 >> 20) & 0x1FFFFull);
            const int id1 = (int)(p1 & 0xFFFFFull), d1 = (int)((p1 >> 20) & 0x1FFFFull);

            const float* r0 = Witem + (long)d0 * 128 + col;
            const float* r1 = Witem + (long)d1 * 128 + col;

            float4 it0[4], it1[4], us0[4], us1[4];
#pragma unroll
            for (int j = 0; j < 4; j++) it0[j] = *reinterpret_cast<const float4*>(r0 + j * NDIM);
#pragma unroll
            for (int j = 0; j < 4; j++) it1[j] = *reinterpret_cast<const float4*>(r1 + j * NDIM);
#pragma unroll
            for (int j = 0; j < 4; j++) {
                const int idx = (int)((p0 >> sh[j]) & (u64)mk[j]);
                us0[j] = *reinterpret_cast<const float4*>(&tab[tb[j] + idx * NDIM + col]);
            }
#pragma unroll
            for (int j = 0; j < 4; j++) {
                const int idx = (int)((p1 >> sh[j]) & (u64)mk[j]);
                us1[j] = *reinterpret_cast<const float4*>(&tab[tb[j] + idx * NDIM + col]);
            }

            float a0 = 0.f, a1 = 0.f;
#pragma unroll
            for (int j = 0; j < 4; j++) {
                a0 += it0[j].x * us0[j].x + it0[j].y * us0[j].y
                    + it0[j].z * us0[j].z + it0[j].w * us0[j].w;
                a1 += it1[j].x * us1[j].x + it1[j].y * us1[j].y
                    + it1[j].z * us1[j].z + it1[j].w * us1[j].w;
            }

            a0 += __shfl_xor(a0, 1);  a1 += __shfl_xor(a1, 1);
            a0 += __shfl_xor(a0, 2);  a1 += __shfl_xor(a1, 2);
            a0 += __shfl_xor(a0, 4);  a1 += __shfl_xor(a1, 4);

            if (l8 == 0) {
                if (res) {  // coalesced write in payload order
                    if (v0) res[st + i0] = a0;
                    if (v1) res[st + i1] = a1;
                } else {    // mid path: scattered (R4 behavior)
                    if (v0) out[id0] = a0;
                    if (v1) out[id1] = a1;
                }
            }
        }
    }
}

// ---------- Pass 3: unpermute res -> out, all coalesced ----------
__global__ __launch_bounds__(256)
void unperm_kernel(const float* __restrict__ res, const unsigned short* __restrict__ invl,
                   float* __restrict__ out, int n)
{
    __shared__ float r[SPB];    // 16 KB
    const int t = threadIdx.x, b = blockIdx.x;
    const int g0 = b * SPB;
    const int rem = n - g0;
    const int len = rem < SPB ? rem : SPB;
#pragma unroll
    for (int i = 0; i < 16; i++) {
        const int k = i * 256 + t;
        if (k < len) r[k] = res[g0 + k];
    }
    __syncthreads();
#pragma unroll
    for (int i = 0; i < 16; i++) {
        const int k = i * 256 + t;
        if (k < len) out[g0 + k] = r[invl[g0 + k]];
    }
}

// ---------- Fallback: R1 direct kernel ----------
__global__ __launch_bounds__(256, 8)
void mf_dot_kernel(const int* __restrict__ dow, const int* __restrict__ tim,
                   const int* __restrict__ mon, const int* __restrict__ day,
                   const int* __restrict__ dest,
                   const float* __restrict__ Wdow, const float* __restrict__ Wtim,
                   const float* __restrict__ Wmon, const float* __restrict__ Wday,
                   const float* __restrict__ Witem,
                   float* __restrict__ out, int n_samples)
{
    __shared__ float tab[TAB_TOT];
    const int tid = threadIdx.x;
    for (int i = tid; i < SZ_DOW; i += 256) tab[B_DOW + i] = Wdow[i];
    for (int i = tid; i < SZ_TIM; i += 256) tab[B_TIM + i] = Wtim[i];
    for (int i = tid; i < SZ_MON; i += 256) tab[B_MON + i] = Wmon[i];
    for (int i = tid; i < SZ_DAY; i += 256) tab[B_DAY + i] = Wday[i];
    __syncthreads();
    const int lane = tid & 63, sub = lane & 31, wave = tid >> 6, half = lane >> 5;
    const int t = sub >> 3, dofs = (sub & 7) * 4;
    const int* idxp  = (t == 0) ? dow   : (t == 1) ? tim   : (t == 2) ? mon   : day;
    const int  tbase = (t == 0) ? B_DOW : (t == 1) ? B_TIM : (t == 2) ? B_MON : B_DAY;
    long n = (long)blockIdx.x * 8 + wave * 2 + half;
    const long stride = (long)gridDim.x * 8;
    for (; n < n_samples; n += stride) {
        const int idx = idxp[n];
        const int ds  = dest[n];
        const float4 u  = *reinterpret_cast<const float4*>(&tab[tbase + idx * NDIM + dofs]);
        const float4 it = *reinterpret_cast<const float4*>(&Witem[(long)ds * 128 + sub * 4]);
        float r = u.x * it.x + u.y * it.y + u.z * it.z + u.w * it.w;
        r += __shfl_xor(r, 16); r += __shfl_xor(r, 8); r += __shfl_xor(r, 4);
        r += __shfl_xor(r, 2);  r += __shfl_xor(r, 1);
        if (sub == 0) out[n] = r;
    }
}

extern "C" void kernel_launch(void* const* d_in, const int* in_sizes, int n_in,
                              void* d_out, int out_size, void* d_ws, size_t ws_size,
                              hipStream_t stream)
{
    const int*   dow   = (const int*)d_in[0];
    const int*   tim   = (const int*)d_in[1];
    const int*   mon   = (const int*)d_in[2];
    const int*   day   = (const int*)d_in[3];
    const int*   dest  = (const int*)d_in[4];
    const float* Wdow  = (const float*)d_in[5];
    const float* Wtim  = (const float*)d_in[6];
    const float* Wmon  = (const float*)d_in[7];
    const float* Wday  = (const float*)d_in[8];
    const float* Witem = (const float*)d_in[9];
    float* out = (float*)d_out;

    const int n = in_sizes[0];  // 1048576
    const int cap = NBLK * SPB; // 1<<20

    const size_t off_payload = 64 * 1024;
    const size_t off_invl    = off_payload + (size_t)cap * 8;
    const size_t off_res     = off_invl + (size_t)cap * 2;
    const size_t need_full   = off_res + (size_t)cap * 4;   // ~14.1 MB
    const size_t need_mid    = off_invl;                    // ~8.07 MB

    if ((size_t)ws_size < need_mid || n > cap) {
        hipLaunchKernelGGL(mf_dot_kernel, dim3(2048), dim3(256), 0, stream,
                           dow, tim, mon, day, dest,
                           Wdow, Wtim, Wmon, Wday, Witem, out, n);
        return;
    }

    const bool full = (size_t)ws_size >= need_full;

    int* cntG   = (int*)d_ws;                               // 32 KB
    int* lbaseG = (int*)((char*)d_ws + 32 * 1024);          // 32 KB
    u64* payload = (u64*)((char*)d_ws + off_payload);
    unsigned short* invl = full ? (unsigned short*)((char*)d_ws + off_invl) : nullptr;
    float* res           = full ? (float*)((char*)d_ws + off_res) : nullptr;

    hipLaunchKernelGGL(bin_kernel, dim3(NBLK), dim3(256), 0, stream,
                       dow, tim, mon, day, dest, cntG, lbaseG, payload, invl, n);
    hipLaunchKernelGGL(mf_main_kernel, dim3(2048), dim3(256), 0, stream,
                       payload, Wdow, Wtim, Wmon, Wday, Witem, cntG, lbaseG, res, out);
    if (full)
        hipLaunchKernelGGL(unperm_kernel, dim3(NBLK), dim3(256), 0, stream,
                           res, invl, out, n);
}

// Round 6
// 162.130 us; speedup vs baseline: 1.1321x; 1.0352x over previous
//
#include <hip/hip_runtime.h>

// MatrixFactorization: out[n] = dot(concat(Wdow[dow],Wtim[tim],Wmon[mon],Wday[day]), Witem[dest])
//
// Evidence ladder:
//  R1 direct:        main 91 us, FETCH 297 MB @3.25 TB/s  (random 128B-line miss ceiling)
//  R4 bin32+scatter: main 57 us, FETCH 95 MB, WRITE 32 MB (dirty-line L2 thrash)
//  R5 bin32+res/unperm: main 46 us, FETCH 72 MB, WRITE 5.7 MB; pre/post ~38 us
//    -> pre/post ran at 1 block/CU (latency-starved); main had structural 8-way
//       LDS conflict (all tab rows stride 32 = same bank footprint for 8 groups).
// R6: (a) bin/unperm at SPB=2048 x 512 blocks (2 blocks/CU), index loads hoisted;
//     (b) tab row stride padded 32->36 floats (rotates bank footprint by 4*(idx%8));
//     (c) main grid 4096 (x=bi&7, s=bi>>3), L~64 per (slice,bucket) -> one
//         64-sample round per wave-phase, 16 blocks/CU queued for overlap.
//
// ws: [0,64K) cntG[s*32+q] | [64K,128K) lbaseG | [128K,+8M) payload u64
//     | invl u16 (2MB) | res f32 (4MB)   (~14.2 MB total; fallback if smaller)

constexpr int NDIM = 32;
constexpr int TS   = 36;                  // padded tab row stride (floats)
constexpr int R_DOW = 7, R_TIM = 24, R_MON = 12, R_DAY = 31;
constexpr int B_DOW = 0;
constexpr int B_TIM = B_DOW + R_DOW * TS;   // 252
constexpr int B_MON = B_TIM + R_TIM * TS;   // 1116
constexpr int B_DAY = B_MON + R_MON * TS;   // 1548
constexpr int TAB_TOT = B_DAY + R_DAY * TS; // 2664 floats = 10656 B

constexpr int NB   = 32;      // dest buckets (dest / 3125)
constexpr int DDIV = 3125;
constexpr int NBLK = 512;     // slices
constexpr int SPB  = 2048;    // samples per slice
constexpr int IPT  = SPB / 256;  // 8 items per thread in bin/unperm

typedef unsigned long long u64;

__device__ __forceinline__ void load_tab(float* tab, const float* Wdow, const float* Wtim,
                                         const float* Wmon, const float* Wday) {
    const int t = threadIdx.x;
    for (int i = t; i < R_DOW * NDIM; i += 256) tab[B_DOW + (i >> 5) * TS + (i & 31)] = Wdow[i];
    for (int i = t; i < R_TIM * NDIM; i += 256) tab[B_TIM + (i >> 5) * TS + (i & 31)] = Wtim[i];
    for (int i = t; i < R_MON * NDIM; i += 256) tab[B_MON + (i >> 5) * TS + (i & 31)] = Wmon[i];
    for (int i = t; i < R_DAY * NDIM; i += 256) tab[B_DAY + (i >> 5) * TS + (i & 31)] = Wday[i];
}

// ---------- Pass 1: fused count+scan+scatter per 2048-sample slice ----------
__global__ __launch_bounds__(256, 2)
void bin_kernel(const int* __restrict__ dow, const int* __restrict__ tim,
                const int* __restrict__ mon, const int* __restrict__ day,
                const int* __restrict__ dest,
                int* __restrict__ cntG, int* __restrict__ lbaseG,
                u64* __restrict__ payload, unsigned short* __restrict__ invl, int n)
{
    __shared__ u64 stage[SPB];              // 16 KB
    __shared__ unsigned short ist[SPB];     // 4 KB
    __shared__ int hist[NB], lbase[NB], cursor[NB];

    const int t = threadIdx.x, b = blockIdx.x;
    const int g0 = b * SPB;
    const int rem = n - g0;
    const int len = rem < SPB ? rem : SPB;

    // hoist ALL index loads up-front (5 independent streams, 40 loads in flight)
    int dreg[IPT], pkreg[IPT];
#pragma unroll
    for (int i = 0; i < IPT; i++) {
        const int k = i * 256 + t;
        if (k < len) {
            const int idx = g0 + k;
            dreg[i]  = dest[idx];
            pkreg[i] = dow[idx] | (tim[idx] << 3) | (mon[idx] << 8) | (day[idx] << 12);
        } else { dreg[i] = -1; pkreg[i] = 0; }
    }
    if (t < NB) hist[t] = 0;
    __syncthreads();
#pragma unroll
    for (int i = 0; i < IPT; i++)
        if (dreg[i] >= 0) atomicAdd(&hist[dreg[i] / DDIV], 1);
    __syncthreads();
    if (t == 0) {
        int run = 0;
        for (int q = 0; q < NB; q++) { lbase[q] = run; run += hist[q]; }
    }
    __syncthreads();
    if (t < NB) { cursor[t] = lbase[t]; cntG[b * NB + t] = hist[t]; lbaseG[b * NB + t] = lbase[t]; }
    __syncthreads();
#pragma unroll
    for (int i = 0; i < IPT; i++) {
        const int k = i * 256 + t;
        if (k < len) {
            const int ds = dreg[i];
            const int j  = atomicAdd(&cursor[ds / DDIV], 1);   // LDS atomic only
            stage[j] = (u64)(unsigned)(g0 + k)
                     | ((u64)(unsigned)ds       << 20)
                     | ((u64)(unsigned)pkreg[i] << 37);
            ist[k] = (unsigned short)j;
        }
    }
    __syncthreads();
#pragma unroll
    for (int i = 0; i < IPT; i++) {
        const int k = i * 256 + t;
        if (k < len) {
            payload[g0 + k] = stage[k];    // coalesced
            invl[g0 + k]    = ist[k];      // coalesced
        }
    }
}

// ---------- Pass 2: XCD-phased binned dot product ----------
__global__ __launch_bounds__(256, 8)
void mf_main_kernel(const u64* __restrict__ payload,
                    const float* __restrict__ Wdow, const float* __restrict__ Wtim,
                    const float* __restrict__ Wmon, const float* __restrict__ Wday,
                    const float* __restrict__ Witem,
                    const int* __restrict__ cntG, const int* __restrict__ lbaseG,
                    float* __restrict__ res)
{
    __shared__ float tab[TAB_TOT];
    load_tab(tab, Wdow, Wtim, Wmon, Wday);
    __syncthreads();

    const int tid = threadIdx.x;
    const int sub = tid & 63;
    const int wv  = tid >> 6;       // wave 0..3
    const int g   = sub >> 3;       // 8-lane group 0..7
    const int l8  = sub & 7;
    const int col = l8 * 4;
    const int tb[4] = {B_DOW, B_TIM, B_MON, B_DAY};
    const int sh[4] = {37, 40, 45, 49};
    const int mk[4] = {7, 31, 15, 31};

    const int x = blockIdx.x & 7;   // intended XCD
    const int s = blockIdx.x >> 3;  // slice 0..511

    for (int p = 0; p < 4; p++) {
        const int q  = x + 8 * p;
        const int L  = cntG[s * NB + q];
        const int st = s * SPB + lbaseG[s * NB + q];

        for (int i = wv * 16; i < L; i += 64) {
            const int i0 = i + g, i1 = i + 8 + g;
            const bool v0 = i0 < L, v1 = i1 < L;

            const u64 p0 = v0 ? payload[st + i0] : 0ull;
            const u64 p1 = v1 ? payload[st + i1] : 0ull;

            const int d0 = (int)((p0 >> 20) & 0x1FFFFull);
            const int d1 = (int)((p1 >> 20) & 0x1FFFFull);

            const float* r0 = Witem + (long)d0 * 128 + col;
            const float* r1 = Witem + (long)d1 * 128 + col;

            float4 it0[4], it1[4], us0[4], us1[4];
#pragma unroll
            for (int j = 0; j < 4; j++) it0[j] = *reinterpret_cast<const float4*>(r0 + j * NDIM);
#pragma unroll
            for (int j = 0; j < 4; j++) it1[j] = *reinterpret_cast<const float4*>(r1 + j * NDIM);
#pragma unroll
            for (int j = 0; j < 4; j++) {
                const int idx = (int)((p0 >> sh[j]) & (u64)mk[j]);
                us0[j] = *reinterpret_cast<const float4*>(&tab[tb[j] + idx * TS + col]);
            }
#pragma unroll
            for (int j = 0; j < 4; j++) {
                const int idx = (int)((p1 >> sh[j]) & (u64)mk[j]);
                us1[j] = *reinterpret_cast<const float4*>(&tab[tb[j] + idx * TS + col]);
            }

            float a0 = 0.f, a1 = 0.f;
#pragma unroll
            for (int j = 0; j < 4; j++) {
                a0 += it0[j].x * us0[j].x + it0[j].y * us0[j].y
                    + it0[j].z * us0[j].z + it0[j].w * us0[j].w;
                a1 += it1[j].x * us1[j].x + it1[j].y * us1[j].y
                    + it1[j].z * us1[j].z + it1[j].w * us1[j].w;
            }

            a0 += __shfl_xor(a0, 1);  a1 += __shfl_xor(a1, 1);
            a0 += __shfl_xor(a0, 2);  a1 += __shfl_xor(a1, 2);
            a0 += __shfl_xor(a0, 4);  a1 += __shfl_xor(a1, 4);

            if (l8 == 0) {              // coalesced, payload-order
                if (v0) res[st + i0] = a0;
                if (v1) res[st + i1] = a1;
            }
        }
    }
}

// ---------- Pass 3: unpermute res -> out ----------
__global__ __launch_bounds__(256, 2)
void unperm_kernel(const float* __restrict__ res, const unsigned short* __restrict__ invl,
                   float* __restrict__ out, int n)
{
    __shared__ float r[SPB];    // 8 KB
    const int t = threadIdx.x, b = blockIdx.x;
    const int g0 = b * SPB;
    const int rem = n - g0;
    const int len = rem < SPB ? rem : SPB;
#pragma unroll
    for (int i = 0; i < IPT; i++) {
        const int k = i * 256 + t;
        if (k < len) r[k] = res[g0 + k];
    }
    __syncthreads();
#pragma unroll
    for (int i = 0; i < IPT; i++) {
        const int k = i * 256 + t;
        if (k < len) out[g0 + k] = r[invl[g0 + k]];
    }
}

// ---------- Fallback: R1 direct kernel ----------
__global__ __launch_bounds__(256, 8)
void mf_dot_kernel(const int* __restrict__ dow, const int* __restrict__ tim,
                   const int* __restrict__ mon, const int* __restrict__ day,
                   const int* __restrict__ dest,
                   const float* __restrict__ Wdow, const float* __restrict__ Wtim,
                   const float* __restrict__ Wmon, const float* __restrict__ Wday,
                   const float* __restrict__ Witem,
                   float* __restrict__ out, int n_samples)
{
    __shared__ float tab[TAB_TOT];
    load_tab(tab, Wdow, Wtim, Wmon, Wday);
    __syncthreads();
    const int tid = threadIdx.x;
    const int lane = tid & 63, sub = lane & 31, wave = tid >> 6, half = lane >> 5;
    const int t = sub >> 3, dofs = (sub & 7) * 4;
    const int* idxp  = (t == 0) ? dow   : (t == 1) ? tim   : (t == 2) ? mon   : day;
    const int  tbase = (t == 0) ? B_DOW : (t == 1) ? B_TIM : (t == 2) ? B_MON : B_DAY;
    long n = (long)blockIdx.x * 8 + wave * 2 + half;
    const long stride = (long)gridDim.x * 8;
    for (; n < n_samples; n += stride) {
        const int idx = idxp[n];
        const int ds  = dest[n];
        const float4 u  = *reinterpret_cast<const float4*>(&tab[tbase + idx * TS + dofs]);
        const float4 it = *reinterpret_cast<const float4*>(&Witem[(long)ds * 128 + sub * 4]);
        float r = u.x * it.x + u.y * it.y + u.z * it.z + u.w * it.w;
        r += __shfl_xor(r, 16); r += __shfl_xor(r, 8); r += __shfl_xor(r, 4);
        r += __shfl_xor(r, 2);  r += __shfl_xor(r, 1);
        if (sub == 0) out[n] = r;
    }
}

extern "C" void kernel_launch(void* const* d_in, const int* in_sizes, int n_in,
                              void* d_out, int out_size, void* d_ws, size_t ws_size,
                              hipStream_t stream)
{
    const int*   dow   = (const int*)d_in[0];
    const int*   tim   = (const int*)d_in[1];
    const int*   mon   = (const int*)d_in[2];
    const int*   day   = (const int*)d_in[3];
    const int*   dest  = (const int*)d_in[4];
    const float* Wdow  = (const float*)d_in[5];
    const float* Wtim  = (const float*)d_in[6];
    const float* Wmon  = (const float*)d_in[7];
    const float* Wday  = (const float*)d_in[8];
    const float* Witem = (const float*)d_in[9];
    float* out = (float*)d_out;

    const int n = in_sizes[0];  // 1048576
    const int cap = NBLK * SPB; // 1<<20

    const size_t off_payload = 128 * 1024;                    // cntG 64K + lbaseG 64K
    const size_t off_invl    = off_payload + (size_t)cap * 8;
    const size_t off_res     = off_invl + (size_t)cap * 2;
    const size_t need        = off_res + (size_t)cap * 4;     // ~14.2 MB

    if ((size_t)ws_size < need || n > cap) {
        hipLaunchKernelGGL(mf_dot_kernel, dim3(2048), dim3(256), 0, stream,
                           dow, tim, mon, day, dest,
                           Wdow, Wtim, Wmon, Wday, Witem, out, n);
        return;
    }

    int* cntG    = (int*)d_ws;
    int* lbaseG  = (int*)((char*)d_ws + 64 * 1024);
    u64* payload = (u64*)((char*)d_ws + off_payload);
    unsigned short* invl = (unsigned short*)((char*)d_ws + off_invl);
    float* res           = (float*)((char*)d_ws + off_res);

    hipLaunchKernelGGL(bin_kernel, dim3(NBLK), dim3(256), 0, stream,
                       dow, tim, mon, day, dest, cntG, lbaseG, payload, invl, n);
    hipLaunchKernelGGL(mf_main_kernel, dim3(NBLK * 8), dim3(256), 0, stream,
                       payload, Wdow, Wtim, Wmon, Wday, Witem, cntG, lbaseG, res);
    hipLaunchKernelGGL(unperm_kernel, dim3(NBLK), dim3(256), 0, stream,
                       res, invl, out, n);
}

// Round 7
// 153.916 us; speedup vs baseline: 1.1926x; 1.0534x over previous
//
#include <hip/hip_runtime.h>

// MatrixFactorization: out[n] = dot(concat(Wdow[dow],Wtim[tim],Wmon[mon],Wday[day]), Witem[dest])
//
// Evidence ladder:
//  R1 direct:           main 91 us, FETCH 297 MB @3.25 TB/s (random-line miss ceiling)
//  R5 bin32+res/unperm: main 46 us, FETCH 72 MB  (best main so far; SPB=4096, grid 2048)
//  R6 pad36+grid4096:   main 51 us, FETCH 98 MB  -> REGRESSION. Bank-conflict counter is
//     ~2 us device-wide (phantom); halving L killed intra-wave ILP; 2x grid smeared phases.
// R7: revert to R5 main shape; raise concurrency:
//   - main: SPB=4096 (L~128 -> 2 iters/wave/phase), grid 2048, launch_bounds(256,8)
//     (VGPR 32 -> up to 32 waves/CU), phase loop unrolled for cross-phase ILP.
//   - bin/unperm: 1024 threads x 256 blocks (16 waves/CU, hoisted loads) instead of
//     256 threads (4-8 waves/CU) -- they were latency-starved, not BW-bound.
//
// ws: [0,32K) cntG[s*32+q] | [32K,64K) lbaseG | [64K,+8M) payload u64
//     | invl u16 (2MB) | res f32 (4MB)  (~14.1 MB; fallback to direct kernel if less)

constexpr int NDIM = 32;
constexpr int SZ_DOW = 7 * NDIM, SZ_TIM = 24 * NDIM, SZ_MON = 12 * NDIM, SZ_DAY = 31 * NDIM;
constexpr int B_DOW = 0;
constexpr int B_TIM = B_DOW + SZ_DOW;   // 224
constexpr int B_MON = B_TIM + SZ_TIM;   // 992
constexpr int B_DAY = B_MON + SZ_MON;   // 1376
constexpr int TAB_TOT = B_DAY + SZ_DAY; // 2368 floats = 9472 B

constexpr int NB    = 32;       // dest buckets (dest / 3125)
constexpr int DDIV  = 3125;
constexpr int NBLK  = 256;      // slices
constexpr int SPB   = 4096;     // samples per slice (L per (slice,bucket) ~ 128)
constexpr int BIN_T = 1024;     // threads for bin/unperm blocks
constexpr int IPT   = SPB / BIN_T;   // 4

typedef unsigned long long u64;

__device__ __forceinline__ void load_tab(float* tab, const float* Wdow, const float* Wtim,
                                         const float* Wmon, const float* Wday, int nthr) {
    const int t = threadIdx.x;
    for (int i = t; i < SZ_DOW; i += nthr) tab[B_DOW + i] = Wdow[i];
    for (int i = t; i < SZ_TIM; i += nthr) tab[B_TIM + i] = Wtim[i];
    for (int i = t; i < SZ_MON; i += nthr) tab[B_MON + i] = Wmon[i];
    for (int i = t; i < SZ_DAY; i += nthr) tab[B_DAY + i] = Wday[i];
}

// ---------- Pass 1: fused count+scan+scatter per 4096-sample slice, 1024 threads ----------
__global__ __launch_bounds__(BIN_T)
void bin_kernel(const int* __restrict__ dow, const int* __restrict__ tim,
                const int* __restrict__ mon, const int* __restrict__ day,
                const int* __restrict__ dest,
                int* __restrict__ cntG, int* __restrict__ lbaseG,
                u64* __restrict__ payload, unsigned short* __restrict__ invl, int n)
{
    __shared__ u64 stage[SPB];              // 32 KB
    __shared__ unsigned short ist[SPB];     // 8 KB
    __shared__ int hist[NB], lbase[NB], cursor[NB];

    const int t = threadIdx.x, b = blockIdx.x;
    const int g0 = b * SPB;
    const int rem = n - g0;
    const int len = rem < SPB ? rem : SPB;

    // hoist ALL index loads up-front (5 independent streams x IPT = 20 loads in flight)
    int dreg[IPT], pkreg[IPT];
#pragma unroll
    for (int i = 0; i < IPT; i++) {
        const int k = i * BIN_T + t;
        if (k < len) {
            const int idx = g0 + k;
            dreg[i]  = dest[idx];
            pkreg[i] = dow[idx] | (tim[idx] << 3) | (mon[idx] << 8) | (day[idx] << 12);
        } else { dreg[i] = -1; pkreg[i] = 0; }
    }
    if (t < NB) hist[t] = 0;
    __syncthreads();
#pragma unroll
    for (int i = 0; i < IPT; i++)
        if (dreg[i] >= 0) atomicAdd(&hist[dreg[i] / DDIV], 1);
    __syncthreads();
    if (t == 0) {
        int run = 0;
        for (int q = 0; q < NB; q++) { lbase[q] = run; run += hist[q]; }
    }
    __syncthreads();
    if (t < NB) { cursor[t] = lbase[t]; cntG[b * NB + t] = hist[t]; lbaseG[b * NB + t] = lbase[t]; }
    __syncthreads();
#pragma unroll
    for (int i = 0; i < IPT; i++) {
        const int k = i * BIN_T + t;
        if (k < len) {
            const int ds = dreg[i];
            const int j  = atomicAdd(&cursor[ds / DDIV], 1);   // LDS atomic only
            stage[j] = (u64)(unsigned)(g0 + k)
                     | ((u64)(unsigned)ds       << 20)
                     | ((u64)(unsigned)pkreg[i] << 37);
            ist[k] = (unsigned short)j;
        }
    }
    __syncthreads();
#pragma unroll
    for (int i = 0; i < IPT; i++) {
        const int k = i * BIN_T + t;
        if (k < len) {
            payload[g0 + k] = stage[k];    // coalesced
            invl[g0 + k]    = ist[k];      // coalesced
        }
    }
}

// ---------- Pass 2: XCD-phased binned dot product ----------
__global__ __launch_bounds__(256, 8)
void mf_main_kernel(const u64* __restrict__ payload,
                    const float* __restrict__ Wdow, const float* __restrict__ Wtim,
                    const float* __restrict__ Wmon, const float* __restrict__ Wday,
                    const float* __restrict__ Witem,
                    const int* __restrict__ cntG, const int* __restrict__ lbaseG,
                    float* __restrict__ res)
{
    __shared__ float tab[TAB_TOT];
    load_tab(tab, Wdow, Wtim, Wmon, Wday, 256);
    __syncthreads();

    const int tid = threadIdx.x;
    const int sub = tid & 63;
    const int wv  = tid >> 6;       // wave 0..3
    const int g   = sub >> 3;       // 8-lane group 0..7
    const int l8  = sub & 7;
    const int col = l8 * 4;
    const int tb[4] = {B_DOW, B_TIM, B_MON, B_DAY};
    const int sh[4] = {37, 40, 45, 49};
    const int mk[4] = {7, 31, 15, 31};

    const int x = blockIdx.x & 7;   // intended XCD
    const int s = blockIdx.x >> 3;  // slice 0..255

    // preload all 4 phases' (L, st) so cross-phase loads can overlap
    int Ls[4], sts[4];
#pragma unroll
    for (int p = 0; p < 4; p++) {
        const int q = x + 8 * p;
        Ls[p]  = cntG[s * NB + q];
        sts[p] = s * SPB + lbaseG[s * NB + q];
    }

#pragma unroll
    for (int p = 0; p < 4; p++) {
        const int L  = Ls[p];
        const int st = sts[p];

        for (int i = wv * 16; i < L; i += 64) {
            const int i0 = i + g, i1 = i + 8 + g;
            const bool v0 = i0 < L, v1 = i1 < L;

            const u64 p0 = v0 ? payload[st + i0] : 0ull;
            const u64 p1 = v1 ? payload[st + i1] : 0ull;

            const int d0 = (int)((p0 >> 20) & 0x1FFFFull);
            const int d1 = (int)((p1 >> 20) & 0x1FFFFull);

            const float* r0 = Witem + (long)d0 * 128 + col;
            const float* r1 = Witem + (long)d1 * 128 + col;

            float4 it0[4], it1[4], us0[4], us1[4];
#pragma unroll
            for (int j = 0; j < 4; j++) it0[j] = *reinterpret_cast<const float4*>(r0 + j * NDIM);
#pragma unroll
            for (int j = 0; j < 4; j++) it1[j] = *reinterpret_cast<const float4*>(r1 + j * NDIM);
#pragma unroll
            for (int j = 0; j < 4; j++) {
                const int idx = (int)((p0 >> sh[j]) & (u64)mk[j]);
                us0[j] = *reinterpret_cast<const float4*>(&tab[tb[j] + idx * NDIM + col]);
            }
#pragma unroll
            for (int j = 0; j < 4; j++) {
                const int idx = (int)((p1 >> sh[j]) & (u64)mk[j]);
                us1[j] = *reinterpret_cast<const float4*>(&tab[tb[j] + idx * NDIM + col]);
            }

            float a0 = 0.f, a1 = 0.f;
#pragma unroll
            for (int j = 0; j < 4; j++) {
                a0 += it0[j].x * us0[j].x + it0[j].y * us0[j].y
                    + it0[j].z * us0[j].z + it0[j].w * us0[j].w;
                a1 += it1[j].x * us1[j].x + it1[j].y * us1[j].y
                    + it1[j].z * us1[j].z + it1[j].w * us1[j].w;
            }

            a0 += __shfl_xor(a0, 1);  a1 += __shfl_xor(a1, 1);
            a0 += __shfl_xor(a0, 2);  a1 += __shfl_xor(a1, 2);
            a0 += __shfl_xor(a0, 4);  a1 += __shfl_xor(a1, 4);

            if (l8 == 0) {              // coalesced, payload-order
                if (v0) res[st + i0] = a0;
                if (v1) res[st + i1] = a1;
            }
        }
    }
}

// ---------- Pass 3: unpermute res -> out, 1024 threads ----------
__global__ __launch_bounds__(BIN_T)
void unperm_kernel(const float* __restrict__ res, const unsigned short* __restrict__ invl,
                   float* __restrict__ out, int n)
{
    __shared__ float r[SPB];    // 16 KB
    const int t = threadIdx.x, b = blockIdx.x;
    const int g0 = b * SPB;
    const int rem = n - g0;
    const int len = rem < SPB ? rem : SPB;

    unsigned short iv[IPT];
#pragma unroll
    for (int i = 0; i < IPT; i++) {     // hoist both streams
        const int k = i * BIN_T + t;
        iv[i] = (k < len) ? invl[g0 + k] : 0;
        if (k < len) r[k] = res[g0 + k];
    }
    __syncthreads();
#pragma unroll
    for (int i = 0; i < IPT; i++) {
        const int k = i * BIN_T + t;
        if (k < len) out[g0 + k] = r[iv[i]];
    }
}

// ---------- Fallback: R1 direct kernel ----------
__global__ __launch_bounds__(256, 8)
void mf_dot_kernel(const int* __restrict__ dow, const int* __restrict__ tim,
                   const int* __restrict__ mon, const int* __restrict__ day,
                   const int* __restrict__ dest,
                   const float* __restrict__ Wdow, const float* __restrict__ Wtim,
                   const float* __restrict__ Wmon, const float* __restrict__ Wday,
                   const float* __restrict__ Witem,
                   float* __restrict__ out, int n_samples)
{
    __shared__ float tab[TAB_TOT];
    load_tab(tab, Wdow, Wtim, Wmon, Wday, 256);
    __syncthreads();
    const int tid = threadIdx.x;
    const int lane = tid & 63, sub = lane & 31, wave = tid >> 6, half = lane >> 5;
    const int t = sub >> 3, dofs = (sub & 7) * 4;
    const int* idxp  = (t == 0) ? dow   : (t == 1) ? tim   : (t == 2) ? mon   : day;
    const int  tbase = (t == 0) ? B_DOW : (t == 1) ? B_TIM : (t == 2) ? B_MON : B_DAY;
    long n = (long)blockIdx.x * 8 + wave * 2 + half;
    const long stride = (long)gridDim.x * 8;
    for (; n < n_samples; n += stride) {
        const int idx = idxp[n];
        const int ds  = dest[n];
        const float4 u  = *reinterpret_cast<const float4*>(&tab[tbase + idx * NDIM + dofs]);
        const float4 it = *reinterpret_cast<const float4*>(&Witem[(long)ds * 128 + sub * 4]);
        float r = u.x * it.x + u.y * it.y + u.z * it.z + u.w * it.w;
        r += __shfl_xor(r, 16); r += __shfl_xor(r, 8); r += __shfl_xor(r, 4);
        r += __shfl_xor(r, 2);  r += __shfl_xor(r, 1);
        if (sub == 0) out[n] = r;
    }
}

extern "C" void kernel_launch(void* const* d_in, const int* in_sizes, int n_in,
                              void* d_out, int out_size, void* d_ws, size_t ws_size,
                              hipStream_t stream)
{
    const int*   dow   = (const int*)d_in[0];
    const int*   tim   = (const int*)d_in[1];
    const int*   mon   = (const int*)d_in[2];
    const int*   day   = (const int*)d_in[3];
    const int*   dest  = (const int*)d_in[4];
    const float* Wdow  = (const float*)d_in[5];
    const float* Wtim  = (const float*)d_in[6];
    const float* Wmon  = (const float*)d_in[7];
    const float* Wday  = (const float*)d_in[8];
    const float* Witem = (const float*)d_in[9];
    float* out = (float*)d_out;

    const int n = in_sizes[0];  // 1048576
    const int cap = NBLK * SPB; // 1<<20

    const size_t off_payload = 64 * 1024;                     // cntG 32K + lbaseG 32K
    const size_t off_invl    = off_payload + (size_t)cap * 8;
    const size_t off_res     = off_invl + (size_t)cap * 2;
    const size_t need        = off_res + (size_t)cap * 4;     // ~14.1 MB

    if ((size_t)ws_size < need || n > cap) {
        hipLaunchKernelGGL(mf_dot_kernel, dim3(2048), dim3(256), 0, stream,
                           dow, tim, mon, day, dest,
                           Wdow, Wtim, Wmon, Wday, Witem, out, n);
        return;
    }

    int* cntG    = (int*)d_ws;
    int* lbaseG  = (int*)((char*)d_ws + 32 * 1024);
    u64* payload = (u64*)((char*)d_ws + off_payload);
    unsigned short* invl = (unsigned short*)((char*)d_ws + off_invl);
    float* res           = (float*)((char*)d_ws + off_res);

    hipLaunchKernelGGL(bin_kernel, dim3(NBLK), dim3(BIN_T), 0, stream,
                       dow, tim, mon, day, dest, cntG, lbaseG, payload, invl, n);
    hipLaunchKernelGGL(mf_main_kernel, dim3(NBLK * 8), dim3(256), 0, stream,
                       payload, Wdow, Wtim, Wmon, Wday, Witem, cntG, lbaseG, res);
    hipLaunchKernelGGL(unperm_kernel, dim3(NBLK), dim3(BIN_T), 0, stream,
                       res, invl, out, n);
}